// Round 4
// baseline (321.974 us; speedup 1.0000x reference)
//
#include <hip/hip_runtime.h>

typedef unsigned short u16;
typedef unsigned int   u32;

typedef __bf16 bf16x8 __attribute__((ext_vector_type(8)));
typedef float  f32x4  __attribute__((ext_vector_type(4)));

typedef const __attribute__((address_space(1))) void* gas_ptr;
typedef __attribute__((address_space(3))) void* las_ptr;

__device__ __forceinline__ u16 f2bf(float f) {
  u32 u = __builtin_bit_cast(u32, f);
  u += 0x7fffu + ((u >> 16) & 1u);
  return (u16)(u >> 16);
}
__device__ __forceinline__ float bf2f(u16 u) {
  return __builtin_bit_cast(float, ((u32)u) << 16);
}
__device__ __forceinline__ u32 pk2(float a, float b) {
  return (u32)f2bf(a) | ((u32)f2bf(b) << 16);
}

// ---------------------------------------------------------------------------
// Kernel 1: BatchNorm over F-channels (stats over B,E) + bf16 cast.
// ---------------------------------------------------------------------------
__global__ __launch_bounds__(256) void bn_norm_kernel(
    const float* __restrict__ x, const float* __restrict__ gamma,
    const float* __restrict__ beta, u16* __restrict__ xn) {
  const int F = 1024, E = 1024;
  int f = blockIdx.x;
  __shared__ float sh[8192];
  __shared__ float ps[4], pq[4], sc[2];

  const float* xf = x + (size_t)f * E;
  float ls = 0.f, lq = 0.f;
  for (int i = threadIdx.x; i < 8192; i += 256) {
    int b = i >> 10, e = i & 1023;
    float v = xf[(size_t)b * F * E + e];
    sh[i] = v;
    ls += v;
    lq += v * v;
  }
  #pragma unroll
  for (int o = 32; o > 0; o >>= 1) {
    ls += __shfl_down(ls, o, 64);
    lq += __shfl_down(lq, o, 64);
  }
  int w = threadIdx.x >> 6;
  if ((threadIdx.x & 63) == 0) { ps[w] = ls; pq[w] = lq; }
  __syncthreads();
  if (threadIdx.x == 0) {
    float s = ps[0] + ps[1] + ps[2] + ps[3];
    float q = pq[0] + pq[1] + pq[2] + pq[3];
    float mean = s * (1.f / 8192.f);
    float var = q * (1.f / 8192.f) - mean * mean;
    float scale = gamma[f] * rsqrtf(var + 1e-5f);
    sc[0] = scale;
    sc[1] = beta[f] - mean * scale;
  }
  __syncthreads();
  float scale = sc[0], shift = sc[1];
  for (int i = threadIdx.x; i < 8192; i += 256) {
    int b = i >> 10, e = i & 1023;
    xn[((size_t)(b * F + f)) * E + e] = f2bf(sh[i] * scale + shift);
  }
}

// ---------------------------------------------------------------------------
// Kernel 2: W_qkv f32 -> bf16
// ---------------------------------------------------------------------------
__global__ __launch_bounds__(256) void wconv_kernel(
    const float* __restrict__ W, u16* __restrict__ Wb) {
  const int total = 3072 * 1024 / 4;
  for (int i = blockIdx.x * 256 + threadIdx.x; i < total; i += gridDim.x * 256) {
    float4 v = ((const float4*)W)[i];
    ushort4 o;
    o.x = f2bf(v.x); o.y = f2bf(v.y); o.z = f2bf(v.z); o.w = f2bf(v.w);
    ((ushort4*)Wb)[i] = o;
  }
}

// ---------------------------------------------------------------------------
// Kernel 3: GEMM  C[m][n] = sum_k A[m][k]*Bw[n][k] + bias[n]  (m97 structure)
// ---------------------------------------------------------------------------
__global__ __launch_bounds__(256) void gemm_qkv_kernel(
    const u16* __restrict__ A, const u16* __restrict__ Bw,
    const float* __restrict__ bias, u16* __restrict__ C) {
  const int K = 1024, N = 3072;
  __shared__ u16 As[128 * 32];
  __shared__ u16 Bs[128 * 32];

  int m0 = blockIdx.x * 128, n0 = blockIdx.y * 128;
  int t = threadIdx.x, lane = t & 63, w = t >> 6;
  int wr = w >> 1, wc = w & 1;
  int r = lane & 15, g = lane >> 4;

  int srow = t >> 2, scol = (t & 3) * 8;
  const u16* gA  = A  + (size_t)(m0 + srow) * K + scol;
  const u16* gA2 = gA + (size_t)64 * K;
  const u16* gB  = Bw + (size_t)(n0 + srow) * K + scol;
  const u16* gB2 = gB + (size_t)64 * K;
  u16* lA  = As + t * 8;
  u16* lA2 = As + 2048 + t * 8;
  u16* lB  = Bs + t * 8;
  u16* lB2 = Bs + 2048 + t * 8;

  f32x4 acc[4][4] = {};

  const u16* pA = As + (size_t)(wr * 64 + r) * 32 + g * 8;
  const u16* pB = Bs + (size_t)(wc * 64 + r) * 32 + g * 8;

  for (int k0 = 0; k0 < K; k0 += 32) {
    __builtin_amdgcn_global_load_lds((gas_ptr)gA,  (las_ptr)lA,  16, 0, 0);
    __builtin_amdgcn_global_load_lds((gas_ptr)gA2, (las_ptr)lA2, 16, 0, 0);
    __builtin_amdgcn_global_load_lds((gas_ptr)gB,  (las_ptr)lB,  16, 0, 0);
    __builtin_amdgcn_global_load_lds((gas_ptr)gB2, (las_ptr)lB2, 16, 0, 0);
    gA += 32; gA2 += 32; gB += 32; gB2 += 32;
    __syncthreads();

    bf16x8 af[4], bfr[4];
    #pragma unroll
    for (int mi = 0; mi < 4; ++mi)
      af[mi] = __builtin_bit_cast(bf16x8, *(const int4*)(pA + mi * 512));
    #pragma unroll
    for (int ni = 0; ni < 4; ++ni)
      bfr[ni] = __builtin_bit_cast(bf16x8, *(const int4*)(pB + ni * 512));
    #pragma unroll
    for (int mi = 0; mi < 4; ++mi)
      #pragma unroll
      for (int ni = 0; ni < 4; ++ni)
        acc[mi][ni] = __builtin_amdgcn_mfma_f32_16x16x32_bf16(af[mi], bfr[ni], acc[mi][ni], 0, 0, 0);
    __syncthreads();
  }

  #pragma unroll
  for (int ni = 0; ni < 4; ++ni) {
    int col = n0 + wc * 64 + ni * 16 + r;
    float bv = bias[col];
    #pragma unroll
    for (int mi = 0; mi < 4; ++mi) {
      int row = m0 + wr * 64 + mi * 16 + g * 4;
      #pragma unroll
      for (int j = 0; j < 4; ++j)
        C[(size_t)(row + j) * N + col] = f2bf(acc[mi][ni][j] + bv);
    }
  }
}

// ---------------------------------------------------------------------------
// Kernel 3b: V transpose WITH baked key permutation.
// The QK D-frag slot (g, j) holds key with bits (j2 g1 g0 j1 j0); the PV
// A-operand k-index m has bits (g1 g0 j2 j1 j0). So store
//   Vt[bh][d][kb + m] = V[kb + a(m)][d],  a(m) = bits (m2 m4 m3 m1 m0)
// (rotate bits {4,3,2}: bit2->bit4, bit4->bit3, bit3->bit2).
// Then the in-register P IS the PV B-frag.
// ---------------------------------------------------------------------------
__global__ __launch_bounds__(256) void vt_kernel(
    const u16* __restrict__ qkv, u16* __restrict__ Vt) {
  __shared__ u16 T[64][72];
  int bh = blockIdx.y, b = bh >> 4, h = bh & 15;
  int f0 = blockIdx.x * 64;
  int t = threadIdx.x;
  int fl = t >> 2, c16 = (t & 3) * 16;
  const u16* src = qkv + (size_t)(b * 1024 + f0 + fl) * 3072 + h * 192 + 128 + c16;
  *(int4*)&T[fl][c16]     = *(const int4*)src;
  *(int4*)&T[fl][c16 + 8] = *(const int4*)(src + 8);
  __syncthreads();
  int dl = t >> 2, fc = (t & 3) * 16;
  u16 buf[16];
  #pragma unroll
  for (int j = 0; j < 16; ++j) {
    int c = fc + j;
    int m = c & 31;
    int a = ((m & 4) << 2) | ((m & 16) >> 1) | ((m & 8) >> 1) | (m & 3);
    buf[j] = T[(c & 32) | a][dl];
  }
  u16* dst = Vt + (size_t)bh * 65536 + (size_t)dl * 1024 + f0 + fc;
  *(int4*)dst       = *(int4*)&buf[0];
  *(int4*)(dst + 8) = *(int4*)&buf[8];
}

// ---------------------------------------------------------------------------
// Kernel 4: flash attention v3.
//  - swapped QK^T (q lane-local), permuted Vt makes P the PV B-frag in-register.
//  - cross-tile K prefetch, early in-tile V issue.
//  - defer-max: common path has ZERO cross-lane ops (vcc ballot only).
// ---------------------------------------------------------------------------
__global__ __launch_bounds__(256) void attn_kernel(
    const u16* __restrict__ qkv, const u16* __restrict__ Vt,
    float* __restrict__ out) {
  const int F = 1024, NQ = 3072;
  int bid = blockIdx.x;           // 2048 blocks
  int xcd = bid & 7;
  int li  = bid >> 3;             // 0..255
  int bh  = ((li >> 4) << 3) | xcd;
  int ql  = li & 15;
  int w   = threadIdx.x >> 6;
  int lane = threadIdx.x & 63;
  int q = lane & 15, g = lane >> 4;
  int q0 = (ql * 4 + w) * 16;
  int b = bh >> 4, h = bh & 15;

  const u16* base = qkv + (size_t)b * F * NQ + h * 192;
  const u16* Kp = base + 64;
  const u16* VtBH = Vt + (size_t)bh * 65536;

  __shared__ float outT[4][64][17];

  // Q fragment, pre-scaled by 1/8 * log2(e) -> softmax in exp2 domain
  const float qscale = 0.125f * 1.4426950408889634f;
  bf16x8 Qf0, Qf1;
  {
    const u16* qp = base + (size_t)(q0 + q) * NQ + g * 8;
    union { int4 v; u16 u[8]; } uu0, uu1;
    uu0.v = *(const int4*)(qp);
    uu1.v = *(const int4*)(qp + 32);
    union { u16 u[8]; bf16x8 v; } p0, p1;
    #pragma unroll
    for (int j = 0; j < 8; ++j) {
      p0.u[j] = f2bf(bf2f(uu0.u[j]) * qscale);
      p1.u[j] = f2bf(bf2f(uu1.u[j]) * qscale);
    }
    Qf0 = p0.v; Qf1 = p1.v;
  }

  // per-lane K row base (A-frag rows q / q+16) and Vt row base (d-row q)
  const u16* kl = Kp + (size_t)q * NQ + g * 8;
  const u16* vl = VtBH + (size_t)q * 1024 + g * 8;

  f32x4 accT0 = {}, accT1 = {}, accT2 = {}, accT3 = {};
  float m = -INFINITY, lsum = 0.f;

  // prologue: K(0) into registers
  int4 kc0 = *(const int4*)(kl);
  int4 kc1 = *(const int4*)(kl + 32);
  int4 kc2 = *(const int4*)(kl + 16 * NQ);
  int4 kc3 = *(const int4*)(kl + 16 * NQ + 32);

  for (int kt = 0; kt < 32; ++kt) {
    int kb = kt * 32;
    int nb = (kt < 31 ? kt + 1 : 31) * 32;
    // ---- early V(t) issue (consumed after softmax)
    const u16* vp = vl + kb;
    int4 vc0 = *(const int4*)(vp);
    int4 vc1 = *(const int4*)(vp + 16 * 1024);
    int4 vc2 = *(const int4*)(vp + 32 * 1024);
    int4 vc3 = *(const int4*)(vp + 48 * 1024);
    // ---- K(t+1) prefetch (consumed next iteration)
    const u16* kn = kl + (size_t)nb * NQ;
    int4 kn0 = *(const int4*)(kn);
    int4 kn1 = *(const int4*)(kn + 32);
    int4 kn2 = *(const int4*)(kn + 16 * NQ);
    int4 kn3 = *(const int4*)(kn + 16 * NQ + 32);

    // ---- S^T tile: [32 keys][16 q]
    f32x4 s0 = {0.f, 0.f, 0.f, 0.f};
    f32x4 s1 = {0.f, 0.f, 0.f, 0.f};
    s0 = __builtin_amdgcn_mfma_f32_16x16x32_bf16(__builtin_bit_cast(bf16x8, kc0), Qf0, s0, 0, 0, 0);
    s0 = __builtin_amdgcn_mfma_f32_16x16x32_bf16(__builtin_bit_cast(bf16x8, kc1), Qf1, s0, 0, 0, 0);
    s1 = __builtin_amdgcn_mfma_f32_16x16x32_bf16(__builtin_bit_cast(bf16x8, kc2), Qf0, s1, 0, 0, 0);
    s1 = __builtin_amdgcn_mfma_f32_16x16x32_bf16(__builtin_bit_cast(bf16x8, kc3), Qf1, s1, 0, 0, 0);

    // ---- defer-max online softmax: no cross-lane ops on common path
    float tmx = fmaxf(fmaxf(fmaxf(s0[0], s0[1]), fmaxf(s0[2], s0[3])),
                      fmaxf(fmaxf(s1[0], s1[1]), fmaxf(s1[2], s1[3])));
    if (__any(tmx > m + 8.0f)) {
      float tr = fmaxf(tmx, __shfl_xor(tmx, 16, 64));
      tr = fmaxf(tr, __shfl_xor(tr, 32, 64));
      float mnew = fmaxf(m, tr);
      float alpha = exp2f(m - mnew);
      lsum *= alpha;
      accT0 *= alpha; accT1 *= alpha; accT2 *= alpha; accT3 *= alpha;
      m = mnew;
    }
    float p0 = exp2f(s0[0] - m), p1 = exp2f(s0[1] - m);
    float p2 = exp2f(s0[2] - m), p3 = exp2f(s0[3] - m);
    float p4 = exp2f(s1[0] - m), p5 = exp2f(s1[1] - m);
    float p6 = exp2f(s1[2] - m), p7 = exp2f(s1[3] - m);
    lsum += ((p0 + p1) + (p2 + p3)) + ((p4 + p5) + (p6 + p7));

    // ---- P IS the PV B-frag (keys pre-permuted in Vt)
    union { u32 w4[4]; bf16x8 v; } pb;
    pb.w4[0] = pk2(p0, p1);
    pb.w4[1] = pk2(p2, p3);
    pb.w4[2] = pk2(p4, p5);
    pb.w4[3] = pk2(p6, p7);

    accT0 = __builtin_amdgcn_mfma_f32_16x16x32_bf16(__builtin_bit_cast(bf16x8, vc0), pb.v, accT0, 0, 0, 0);
    accT1 = __builtin_amdgcn_mfma_f32_16x16x32_bf16(__builtin_bit_cast(bf16x8, vc1), pb.v, accT1, 0, 0, 0);
    accT2 = __builtin_amdgcn_mfma_f32_16x16x32_bf16(__builtin_bit_cast(bf16x8, vc2), pb.v, accT2, 0, 0, 0);
    accT3 = __builtin_amdgcn_mfma_f32_16x16x32_bf16(__builtin_bit_cast(bf16x8, vc3), pb.v, accT3, 0, 0, 0);

    kc0 = kn0; kc1 = kn1; kc2 = kn2; kc3 = kn3;
  }

  // ---- epilogue: reduce lsum across the 4 g-lanes, normalize, transpose, store
  lsum += __shfl_xor(lsum, 16, 64);
  lsum += __shfl_xor(lsum, 32, 64);
  float inv = 1.0f / lsum;
  f32x4 at[4] = {accT0, accT1, accT2, accT3};
  #pragma unroll
  for (int dt = 0; dt < 4; ++dt) {
    outT[w][dt * 16 + g * 4 + 0][q] = at[dt][0] * inv;
    outT[w][dt * 16 + g * 4 + 1][q] = at[dt][1] * inv;
    outT[w][dt * 16 + g * 4 + 2][q] = at[dt][2] * inv;
    outT[w][dt * 16 + g * 4 + 3][q] = at[dt][3] * inv;
  }
  asm volatile("s_waitcnt lgkmcnt(0)" ::: "memory");
  int oq = lane >> 2, dc = (lane & 3) * 16;
  float* orow = out + (size_t)(b * F + q0 + oq) * 1024 + h * 64 + dc;
  #pragma unroll
  for (int c4 = 0; c4 < 4; ++c4) {
    float4 v;
    v.x = outT[w][dc + c4 * 4 + 0][oq];
    v.y = outT[w][dc + c4 * 4 + 1][oq];
    v.z = outT[w][dc + c4 * 4 + 2][oq];
    v.w = outT[w][dc + c4 * 4 + 3][oq];
    *(float4*)(orow + c4 * 4) = v;
  }
}

// ---------------------------------------------------------------------------
extern "C" void kernel_launch(void* const* d_in, const int* in_sizes, int n_in,
                              void* d_out, int out_size, void* d_ws, size_t ws_size,
                              hipStream_t stream) {
  const float* x     = (const float*)d_in[0];
  const float* gamma = (const float*)d_in[1];
  const float* beta  = (const float*)d_in[2];
  const float* W     = (const float*)d_in[3];
  const float* bias  = (const float*)d_in[4];
  float* out = (float*)d_out;

  char* ws = (char*)d_ws;
  u16* xn  = (u16*)ws;                                   // 16 MB
  u16* Wb  = (u16*)(ws + (size_t)16 * 1024 * 1024);      //  6 MB
  u16* qkv = (u16*)(ws + (size_t)22 * 1024 * 1024);      // 48 MB
  u16* Vt  = (u16*)(ws + (size_t)70 * 1024 * 1024);      // 16 MB

  bn_norm_kernel<<<1024, 256, 0, stream>>>(x, gamma, beta, xn);
  wconv_kernel<<<768, 256, 0, stream>>>(W, Wb);
  gemm_qkv_kernel<<<dim3(64, 24), 256, 0, stream>>>(xn, Wb, bias, qkv);
  vt_kernel<<<dim3(16, 128), 256, 0, stream>>>(qkv, Vt);
  attn_kernel<<<2048, 256, 0, stream>>>(qkv, Vt, out);
}

// Round 5
// 171.511 us; speedup vs baseline: 1.8773x; 1.8773x over previous
//
#include <hip/hip_runtime.h>

typedef unsigned short u16;
typedef unsigned int   u32;

typedef __bf16 bf16x8 __attribute__((ext_vector_type(8)));
typedef float  f32x4  __attribute__((ext_vector_type(4)));

typedef const __attribute__((address_space(1))) void* gas_ptr;
typedef __attribute__((address_space(3))) void* las_ptr;

__device__ __forceinline__ u16 f2bf(float f) {
  u32 u = __builtin_bit_cast(u32, f);
  u += 0x7fffu + ((u >> 16) & 1u);
  return (u16)(u >> 16);
}
__device__ __forceinline__ float bf2f(u16 u) {
  return __builtin_bit_cast(float, ((u32)u) << 16);
}
__device__ __forceinline__ u32 pk2(float a, float b) {
  return (u32)f2bf(a) | ((u32)f2bf(b) << 16);
}

// ---------------------------------------------------------------------------
// Kernel 1: BatchNorm over F-channels (stats over B,E) + bf16 cast.
// ---------------------------------------------------------------------------
__global__ __launch_bounds__(256) void bn_norm_kernel(
    const float* __restrict__ x, const float* __restrict__ gamma,
    const float* __restrict__ beta, u16* __restrict__ xn) {
  const int F = 1024, E = 1024;
  int f = blockIdx.x;
  __shared__ float sh[8192];
  __shared__ float ps[4], pq[4], sc[2];

  const float* xf = x + (size_t)f * E;
  float ls = 0.f, lq = 0.f;
  for (int i = threadIdx.x; i < 8192; i += 256) {
    int b = i >> 10, e = i & 1023;
    float v = xf[(size_t)b * F * E + e];
    sh[i] = v;
    ls += v;
    lq += v * v;
  }
  #pragma unroll
  for (int o = 32; o > 0; o >>= 1) {
    ls += __shfl_down(ls, o, 64);
    lq += __shfl_down(lq, o, 64);
  }
  int w = threadIdx.x >> 6;
  if ((threadIdx.x & 63) == 0) { ps[w] = ls; pq[w] = lq; }
  __syncthreads();
  if (threadIdx.x == 0) {
    float s = ps[0] + ps[1] + ps[2] + ps[3];
    float q = pq[0] + pq[1] + pq[2] + pq[3];
    float mean = s * (1.f / 8192.f);
    float var = q * (1.f / 8192.f) - mean * mean;
    float scale = gamma[f] * rsqrtf(var + 1e-5f);
    sc[0] = scale;
    sc[1] = beta[f] - mean * scale;
  }
  __syncthreads();
  float scale = sc[0], shift = sc[1];
  for (int i = threadIdx.x; i < 8192; i += 256) {
    int b = i >> 10, e = i & 1023;
    xn[((size_t)(b * F + f)) * E + e] = f2bf(sh[i] * scale + shift);
  }
}

// ---------------------------------------------------------------------------
// Kernel 2: W_qkv f32 -> bf16
// ---------------------------------------------------------------------------
__global__ __launch_bounds__(256) void wconv_kernel(
    const float* __restrict__ W, u16* __restrict__ Wb) {
  const int total = 3072 * 1024 / 4;
  for (int i = blockIdx.x * 256 + threadIdx.x; i < total; i += gridDim.x * 256) {
    float4 v = ((const float4*)W)[i];
    ushort4 o;
    o.x = f2bf(v.x); o.y = f2bf(v.y); o.z = f2bf(v.z); o.w = f2bf(v.w);
    ((ushort4*)Wb)[i] = o;
  }
}

// ---------------------------------------------------------------------------
// Kernel 3: GEMM  C[m][n] = sum_k A[m][k]*Bw[n][k] + bias[n]  (m97 structure)
// ---------------------------------------------------------------------------
__global__ __launch_bounds__(256) void gemm_qkv_kernel(
    const u16* __restrict__ A, const u16* __restrict__ Bw,
    const float* __restrict__ bias, u16* __restrict__ C) {
  const int K = 1024, N = 3072;
  __shared__ u16 As[128 * 32];
  __shared__ u16 Bs[128 * 32];

  int m0 = blockIdx.x * 128, n0 = blockIdx.y * 128;
  int t = threadIdx.x, lane = t & 63, w = t >> 6;
  int wr = w >> 1, wc = w & 1;
  int r = lane & 15, g = lane >> 4;

  int srow = t >> 2, scol = (t & 3) * 8;
  const u16* gA  = A  + (size_t)(m0 + srow) * K + scol;
  const u16* gA2 = gA + (size_t)64 * K;
  const u16* gB  = Bw + (size_t)(n0 + srow) * K + scol;
  const u16* gB2 = gB + (size_t)64 * K;
  u16* lA  = As + t * 8;
  u16* lA2 = As + 2048 + t * 8;
  u16* lB  = Bs + t * 8;
  u16* lB2 = Bs + 2048 + t * 8;

  f32x4 acc[4][4] = {};

  const u16* pA = As + (size_t)(wr * 64 + r) * 32 + g * 8;
  const u16* pB = Bs + (size_t)(wc * 64 + r) * 32 + g * 8;

  for (int k0 = 0; k0 < K; k0 += 32) {
    __builtin_amdgcn_global_load_lds((gas_ptr)gA,  (las_ptr)lA,  16, 0, 0);
    __builtin_amdgcn_global_load_lds((gas_ptr)gA2, (las_ptr)lA2, 16, 0, 0);
    __builtin_amdgcn_global_load_lds((gas_ptr)gB,  (las_ptr)lB,  16, 0, 0);
    __builtin_amdgcn_global_load_lds((gas_ptr)gB2, (las_ptr)lB2, 16, 0, 0);
    gA += 32; gA2 += 32; gB += 32; gB2 += 32;
    __syncthreads();

    bf16x8 af[4], bfr[4];
    #pragma unroll
    for (int mi = 0; mi < 4; ++mi)
      af[mi] = __builtin_bit_cast(bf16x8, *(const int4*)(pA + mi * 512));
    #pragma unroll
    for (int ni = 0; ni < 4; ++ni)
      bfr[ni] = __builtin_bit_cast(bf16x8, *(const int4*)(pB + ni * 512));
    #pragma unroll
    for (int mi = 0; mi < 4; ++mi)
      #pragma unroll
      for (int ni = 0; ni < 4; ++ni)
        acc[mi][ni] = __builtin_amdgcn_mfma_f32_16x16x32_bf16(af[mi], bfr[ni], acc[mi][ni], 0, 0, 0);
    __syncthreads();
  }

  #pragma unroll
  for (int ni = 0; ni < 4; ++ni) {
    int col = n0 + wc * 64 + ni * 16 + r;
    float bv = bias[col];
    #pragma unroll
    for (int mi = 0; mi < 4; ++mi) {
      int row = m0 + wr * 64 + mi * 16 + g * 4;
      #pragma unroll
      for (int j = 0; j < 4; ++j)
        C[(size_t)(row + j) * N + col] = f2bf(acc[mi][ni][j] + bv);
    }
  }
}

// ---------------------------------------------------------------------------
// Kernel 3b: V transpose WITH baked key permutation (verified R3).
//   Vt[bh][d][kb+m] = V[kb + a(m)][d],  a(m) = bits (m2 m4 m3 m1 m0)
// so the in-register QK softmax output IS the PV B-fragment.
// ---------------------------------------------------------------------------
__global__ __launch_bounds__(256) void vt_kernel(
    const u16* __restrict__ qkv, u16* __restrict__ Vt) {
  __shared__ u16 T[64][72];
  int bh = blockIdx.y, b = bh >> 4, h = bh & 15;
  int f0 = blockIdx.x * 64;
  int t = threadIdx.x;
  int fl = t >> 2, c16 = (t & 3) * 16;
  const u16* src = qkv + (size_t)(b * 1024 + f0 + fl) * 3072 + h * 192 + 128 + c16;
  *(int4*)&T[fl][c16]     = *(const int4*)src;
  *(int4*)&T[fl][c16 + 8] = *(const int4*)(src + 8);
  __syncthreads();
  int dl = t >> 2, fc = (t & 3) * 16;
  u16 buf[16];
  #pragma unroll
  for (int j = 0; j < 16; ++j) {
    int c = fc + j;
    int m = c & 31;
    int a = ((m & 4) << 2) | ((m & 16) >> 1) | ((m & 8) >> 1) | (m & 3);
    buf[j] = T[(c & 32) | a][dl];
  }
  u16* dst = Vt + (size_t)bh * 65536 + (size_t)dl * 1024 + f0 + fc;
  *(int4*)dst       = *(int4*)&buf[0];
  *(int4*)(dst + 8) = *(int4*)&buf[8];
}

// ---------------------------------------------------------------------------
// Kernel 4: flash attention v4 — LDS-staged, double-buffered K/V.
//  - 4 waves/block share one (b,h); wave w owns q-rows q0+w*16..+16; KVBLK=64.
//  - K and Vt tiles staged cooperatively via global_load_lds (w16),
//    source pre-swizzled (chunk ^= row&7), linear LDS dest, swizzled ds_read.
//  - prefetch(t+1) issued before compute(t); one barrier per tile.
//  - swapped QK^T, baked-permutation PV (P stays in registers).
//  - epilogue outT aliases the staging LDS.
// ---------------------------------------------------------------------------
__global__ __launch_bounds__(256) void attn_kernel(
    const u16* __restrict__ qkv, const u16* __restrict__ Vt,
    float* __restrict__ out) {
  const int F = 1024, NQ = 3072;
  int bid = blockIdx.x;           // 2048 blocks
  int xcd = bid & 7;
  int li  = bid >> 3;             // 0..255
  int bh  = ((li >> 4) << 3) | xcd;
  int ql  = li & 15;
  int w   = threadIdx.x >> 6;
  int lane = threadIdx.x & 63;
  int q = lane & 15, g = lane >> 4;
  int qs = q & 7;
  int q0 = ql * 64 + w * 16;
  int b = bh >> 4, h = bh & 15;

  const u16* base = qkv + (size_t)b * F * NQ + h * 192;
  const u16* VtBH = Vt + (size_t)bh * 65536;

  // LDS: Kbuf[2] @ 0/4096, Vbuf[2] @ 8192/12288 (u16 units; 8 KB each)
  __shared__ u16 S[16384];

  // staging lane geometry
  int i8 = lane >> 3;     // 0..7 (row within wave's 8-row slice)
  int ic = lane & 7;      // chunk 0..7 (16B units)

  // Q fragment, pre-scaled by 1/8 * log2(e) -> softmax in exp2 domain
  const float qscale = 0.125f * 1.4426950408889634f;
  bf16x8 Qf0, Qf1;
  {
    const u16* qp = base + (size_t)(q0 + q) * NQ + g * 8;
    union { int4 v; u16 u[8]; } uu0, uu1;
    uu0.v = *(const int4*)(qp);
    uu1.v = *(const int4*)(qp + 32);
    union { u16 u[8]; bf16x8 v; } p0, p1;
    #pragma unroll
    for (int j = 0; j < 8; ++j) {
      p0.u[j] = f2bf(bf2f(uu0.u[j]) * qscale);
      p1.u[j] = f2bf(bf2f(uu1.u[j]) * qscale);
    }
    Qf0 = p0.v; Qf1 = p1.v;
  }

  f32x4 acc[4] = {};
  float m = -INFINITY, lsum = 0.f;

  // ---- stage tile kt into buffer buf (all 4 waves cooperate) ----
  #define STAGE(buf, kt)                                                       \
    do {                                                                       \
      int kb_ = (kt) * 64;                                                     \
      _Pragma("unroll")                                                        \
      for (int rr = 0; rr < 2; ++rr) {                                         \
        int r_ = rr * 32 + w * 8 + i8;                                         \
        int sc_ = (ic ^ (r_ & 7)) * 8;                                         \
        const u16* ks_ = base + (size_t)(kb_ + r_) * NQ + 64 + sc_;            \
        const u16* vs_ = VtBH + (size_t)r_ * 1024 + kb_ + sc_;                 \
        __builtin_amdgcn_global_load_lds((gas_ptr)ks_,                         \
            (las_ptr)&S[(buf) * 4096 + (rr * 32 + w * 8) * 64], 16, 0, 0);     \
        __builtin_amdgcn_global_load_lds((gas_ptr)vs_,                         \
            (las_ptr)&S[8192 + (buf) * 4096 + (rr * 32 + w * 8) * 64], 16, 0, 0);\
      }                                                                        \
    } while (0)

  STAGE(0, 0);
  __syncthreads();

  int cur = 0;
  for (int kt = 0; kt < 16; ++kt) {
    if (kt < 15) STAGE(cur ^ 1, kt + 1);

    const u16* Kb = &S[cur * 4096];
    const u16* Vb = &S[8192 + cur * 4096];

    // ---- QK^T: 4 frag-groups of 16 keys, K from swizzled LDS
    f32x4 s[4];
    #pragma unroll
    for (int ks = 0; ks < 4; ++ks) {
      int row = ks * 16 + q;
      int4 k0 = *(const int4*)&Kb[row * 64 + ((g ^ qs) * 8)];
      int4 k1 = *(const int4*)&Kb[row * 64 + (((4 + g) ^ qs) * 8)];
      f32x4 sv = {0.f, 0.f, 0.f, 0.f};
      sv = __builtin_amdgcn_mfma_f32_16x16x32_bf16(__builtin_bit_cast(bf16x8, k0), Qf0, sv, 0, 0, 0);
      sv = __builtin_amdgcn_mfma_f32_16x16x32_bf16(__builtin_bit_cast(bf16x8, k1), Qf1, sv, 0, 0, 0);
      s[ks] = sv;
    }

    // ---- defer-max online softmax over 16 per-lane scores
    float tmx = s[0][0];
    #pragma unroll
    for (int ks = 0; ks < 4; ++ks) {
      tmx = fmaxf(tmx, fmaxf(fmaxf(s[ks][0], s[ks][1]), fmaxf(s[ks][2], s[ks][3])));
    }
    if (__any(tmx > m + 8.0f)) {
      float tr = fmaxf(tmx, __shfl_xor(tmx, 16, 64));
      tr = fmaxf(tr, __shfl_xor(tr, 32, 64));
      float mnew = fmaxf(m, tr);
      float alpha = exp2f(m - mnew);
      lsum *= alpha;
      acc[0] *= alpha; acc[1] *= alpha; acc[2] *= alpha; acc[3] *= alpha;
      m = mnew;
    }
    float p[16];
    #pragma unroll
    for (int ks = 0; ks < 4; ++ks) {
      p[ks * 4 + 0] = exp2f(s[ks][0] - m);
      p[ks * 4 + 1] = exp2f(s[ks][1] - m);
      p[ks * 4 + 2] = exp2f(s[ks][2] - m);
      p[ks * 4 + 3] = exp2f(s[ks][3] - m);
    }
    float psum = 0.f;
    #pragma unroll
    for (int j = 0; j < 16; ++j) psum += p[j];
    lsum += psum;

    // ---- pack P into two PV B-frags (keys pre-permuted in Vt)
    union { u32 w4[4]; bf16x8 v; } pb0, pb1;
    pb0.w4[0] = pk2(p[0], p[1]);   pb0.w4[1] = pk2(p[2], p[3]);
    pb0.w4[2] = pk2(p[4], p[5]);   pb0.w4[3] = pk2(p[6], p[7]);
    pb1.w4[0] = pk2(p[8], p[9]);   pb1.w4[1] = pk2(p[10], p[11]);
    pb1.w4[2] = pk2(p[12], p[13]); pb1.w4[3] = pk2(p[14], p[15]);

    // ---- PV: acc[dt] += Vt_frag · pb  (Vt from swizzled LDS)
    #pragma unroll
    for (int dt = 0; dt < 4; ++dt) {
      int row = dt * 16 + q;
      int4 v0 = *(const int4*)&Vb[row * 64 + ((g ^ qs) * 8)];
      int4 v1 = *(const int4*)&Vb[row * 64 + (((4 + g) ^ qs) * 8)];
      acc[dt] = __builtin_amdgcn_mfma_f32_16x16x32_bf16(__builtin_bit_cast(bf16x8, v0), pb0.v, acc[dt], 0, 0, 0);
      acc[dt] = __builtin_amdgcn_mfma_f32_16x16x32_bf16(__builtin_bit_cast(bf16x8, v1), pb1.v, acc[dt], 0, 0, 0);
    }

    __syncthreads();
    cur ^= 1;
  }
  #undef STAGE

  // ---- epilogue: reduce lsum, normalize, transpose via LDS (aliased), store
  lsum += __shfl_xor(lsum, 16, 64);
  lsum += __shfl_xor(lsum, 32, 64);
  float inv = 1.0f / lsum;

  float* oT = (float*)S + (size_t)w * 1088;   // per-wave 64x17 region
  #pragma unroll
  for (int dt = 0; dt < 4; ++dt) {
    oT[(dt * 16 + g * 4 + 0) * 17 + q] = acc[dt][0] * inv;
    oT[(dt * 16 + g * 4 + 1) * 17 + q] = acc[dt][1] * inv;
    oT[(dt * 16 + g * 4 + 2) * 17 + q] = acc[dt][2] * inv;
    oT[(dt * 16 + g * 4 + 3) * 17 + q] = acc[dt][3] * inv;
  }
  asm volatile("s_waitcnt lgkmcnt(0)" ::: "memory");
  int oq = lane >> 2, dc = (lane & 3) * 16;
  float* orow = out + (size_t)(b * F + q0 + oq) * 1024 + h * 64 + dc;
  #pragma unroll
  for (int c4 = 0; c4 < 4; ++c4) {
    float4 v;
    v.x = oT[(dc + c4 * 4 + 0) * 17 + oq];
    v.y = oT[(dc + c4 * 4 + 1) * 17 + oq];
    v.z = oT[(dc + c4 * 4 + 2) * 17 + oq];
    v.w = oT[(dc + c4 * 4 + 3) * 17 + oq];
    *(float4*)(orow + c4 * 4) = v;
  }
}

// ---------------------------------------------------------------------------
extern "C" void kernel_launch(void* const* d_in, const int* in_sizes, int n_in,
                              void* d_out, int out_size, void* d_ws, size_t ws_size,
                              hipStream_t stream) {
  const float* x     = (const float*)d_in[0];
  const float* gamma = (const float*)d_in[1];
  const float* beta  = (const float*)d_in[2];
  const float* W     = (const float*)d_in[3];
  const float* bias  = (const float*)d_in[4];
  float* out = (float*)d_out;

  char* ws = (char*)d_ws;
  u16* xn  = (u16*)ws;                                   // 16 MB
  u16* Wb  = (u16*)(ws + (size_t)16 * 1024 * 1024);      //  6 MB
  u16* qkv = (u16*)(ws + (size_t)22 * 1024 * 1024);      // 48 MB
  u16* Vt  = (u16*)(ws + (size_t)70 * 1024 * 1024);      // 16 MB

  bn_norm_kernel<<<1024, 256, 0, stream>>>(x, gamma, beta, xn);
  wconv_kernel<<<768, 256, 0, stream>>>(W, Wb);
  gemm_qkv_kernel<<<dim3(64, 24), 256, 0, stream>>>(xn, Wb, bias, qkv);
  vt_kernel<<<dim3(16, 128), 256, 0, stream>>>(qkv, Vt);
  attn_kernel<<<2048, 256, 0, stream>>>(qkv, Vt, out);
}

// Round 6
// 167.655 us; speedup vs baseline: 1.9205x; 1.0230x over previous
//
#include <hip/hip_runtime.h>

typedef unsigned short u16;
typedef unsigned int   u32;

typedef __bf16 bf16x8 __attribute__((ext_vector_type(8)));
typedef float  f32x4  __attribute__((ext_vector_type(4)));

typedef const __attribute__((address_space(1))) void* gas_ptr;
typedef __attribute__((address_space(3))) void* las_ptr;

__device__ __forceinline__ u16 f2bf(float f) {
  u32 u = __builtin_bit_cast(u32, f);
  u += 0x7fffu + ((u >> 16) & 1u);
  return (u16)(u >> 16);
}
__device__ __forceinline__ float bf2f(u16 u) {
  return __builtin_bit_cast(float, ((u32)u) << 16);
}
// packed f32->bf16x2 hardware convert (RTNE), 1 VALU op per pair
__device__ __forceinline__ u32 cvtpk(float a, float b) {
  u32 r;
  asm("v_cvt_pk_bf16_f32 %0, %1, %2" : "=v"(r) : "v"(a), "v"(b));
  return r;
}

// ---------------------------------------------------------------------------
// Kernel 1: BatchNorm over F-channels (stats over B,E) + bf16 cast.
// ---------------------------------------------------------------------------
__global__ __launch_bounds__(256) void bn_norm_kernel(
    const float* __restrict__ x, const float* __restrict__ gamma,
    const float* __restrict__ beta, u16* __restrict__ xn) {
  const int F = 1024, E = 1024;
  int f = blockIdx.x;
  __shared__ float sh[8192];
  __shared__ float ps[4], pq[4], sc[2];

  const float* xf = x + (size_t)f * E;
  float ls = 0.f, lq = 0.f;
  for (int i = threadIdx.x; i < 8192; i += 256) {
    int b = i >> 10, e = i & 1023;
    float v = xf[(size_t)b * F * E + e];
    sh[i] = v;
    ls += v;
    lq += v * v;
  }
  #pragma unroll
  for (int o = 32; o > 0; o >>= 1) {
    ls += __shfl_down(ls, o, 64);
    lq += __shfl_down(lq, o, 64);
  }
  int w = threadIdx.x >> 6;
  if ((threadIdx.x & 63) == 0) { ps[w] = ls; pq[w] = lq; }
  __syncthreads();
  if (threadIdx.x == 0) {
    float s = ps[0] + ps[1] + ps[2] + ps[3];
    float q = pq[0] + pq[1] + pq[2] + pq[3];
    float mean = s * (1.f / 8192.f);
    float var = q * (1.f / 8192.f) - mean * mean;
    float scale = gamma[f] * rsqrtf(var + 1e-5f);
    sc[0] = scale;
    sc[1] = beta[f] - mean * scale;
  }
  __syncthreads();
  float scale = sc[0], shift = sc[1];
  for (int i = threadIdx.x; i < 8192; i += 256) {
    int b = i >> 10, e = i & 1023;
    xn[((size_t)(b * F + f)) * E + e] = f2bf(sh[i] * scale + shift);
  }
}

// ---------------------------------------------------------------------------
// Kernel 2: W_qkv f32 -> bf16
// ---------------------------------------------------------------------------
__global__ __launch_bounds__(256) void wconv_kernel(
    const float* __restrict__ W, u16* __restrict__ Wb) {
  const int total = 3072 * 1024 / 4;
  for (int i = blockIdx.x * 256 + threadIdx.x; i < total; i += gridDim.x * 256) {
    float4 v = ((const float4*)W)[i];
    ushort4 o;
    o.x = f2bf(v.x); o.y = f2bf(v.y); o.z = f2bf(v.z); o.w = f2bf(v.w);
    ((ushort4*)Wb)[i] = o;
  }
}

// ---------------------------------------------------------------------------
// Kernel 3: GEMM  C[m][n] = sum_k A[m][k]*Bw[n][k] + bias[n]  (m97 structure)
// ---------------------------------------------------------------------------
__global__ __launch_bounds__(256) void gemm_qkv_kernel(
    const u16* __restrict__ A, const u16* __restrict__ Bw,
    const float* __restrict__ bias, u16* __restrict__ C) {
  const int K = 1024, N = 3072;
  __shared__ u16 As[128 * 32];
  __shared__ u16 Bs[128 * 32];

  int m0 = blockIdx.x * 128, n0 = blockIdx.y * 128;
  int t = threadIdx.x, lane = t & 63, w = t >> 6;
  int wr = w >> 1, wc = w & 1;
  int r = lane & 15, g = lane >> 4;

  int srow = t >> 2, scol = (t & 3) * 8;
  const u16* gA  = A  + (size_t)(m0 + srow) * K + scol;
  const u16* gA2 = gA + (size_t)64 * K;
  const u16* gB  = Bw + (size_t)(n0 + srow) * K + scol;
  const u16* gB2 = gB + (size_t)64 * K;
  u16* lA  = As + t * 8;
  u16* lA2 = As + 2048 + t * 8;
  u16* lB  = Bs + t * 8;
  u16* lB2 = Bs + 2048 + t * 8;

  f32x4 acc[4][4] = {};

  const u16* pA = As + (size_t)(wr * 64 + r) * 32 + g * 8;
  const u16* pB = Bs + (size_t)(wc * 64 + r) * 32 + g * 8;

  for (int k0 = 0; k0 < K; k0 += 32) {
    __builtin_amdgcn_global_load_lds((gas_ptr)gA,  (las_ptr)lA,  16, 0, 0);
    __builtin_amdgcn_global_load_lds((gas_ptr)gA2, (las_ptr)lA2, 16, 0, 0);
    __builtin_amdgcn_global_load_lds((gas_ptr)gB,  (las_ptr)lB,  16, 0, 0);
    __builtin_amdgcn_global_load_lds((gas_ptr)gB2, (las_ptr)lB2, 16, 0, 0);
    gA += 32; gA2 += 32; gB += 32; gB2 += 32;
    __syncthreads();

    bf16x8 af[4], bfr[4];
    #pragma unroll
    for (int mi = 0; mi < 4; ++mi)
      af[mi] = __builtin_bit_cast(bf16x8, *(const int4*)(pA + mi * 512));
    #pragma unroll
    for (int ni = 0; ni < 4; ++ni)
      bfr[ni] = __builtin_bit_cast(bf16x8, *(const int4*)(pB + ni * 512));
    #pragma unroll
    for (int mi = 0; mi < 4; ++mi)
      #pragma unroll
      for (int ni = 0; ni < 4; ++ni)
        acc[mi][ni] = __builtin_amdgcn_mfma_f32_16x16x32_bf16(af[mi], bfr[ni], acc[mi][ni], 0, 0, 0);
    __syncthreads();
  }

  #pragma unroll
  for (int ni = 0; ni < 4; ++ni) {
    int col = n0 + wc * 64 + ni * 16 + r;
    float bv = bias[col];
    #pragma unroll
    for (int mi = 0; mi < 4; ++mi) {
      int row = m0 + wr * 64 + mi * 16 + g * 4;
      #pragma unroll
      for (int j = 0; j < 4; ++j)
        C[(size_t)(row + j) * N + col] = f2bf(acc[mi][ni][j] + bv);
    }
  }
}

// ---------------------------------------------------------------------------
// Kernel 3b: V transpose WITH baked key permutation (verified R3).
//   Vt[bh][d][kb+m] = V[kb + a(m)][d],  a(m) = bits (m2 m4 m3 m1 m0)
// so the in-register QK softmax output IS the PV B-fragment.
// ---------------------------------------------------------------------------
__global__ __launch_bounds__(256) void vt_kernel(
    const u16* __restrict__ qkv, u16* __restrict__ Vt) {
  __shared__ u16 T[64][72];
  int bh = blockIdx.y, b = bh >> 4, h = bh & 15;
  int f0 = blockIdx.x * 64;
  int t = threadIdx.x;
  int fl = t >> 2, c16 = (t & 3) * 16;
  const u16* src = qkv + (size_t)(b * 1024 + f0 + fl) * 3072 + h * 192 + 128 + c16;
  *(int4*)&T[fl][c16]     = *(const int4*)src;
  *(int4*)&T[fl][c16 + 8] = *(const int4*)(src + 8);
  __syncthreads();
  int dl = t >> 2, fc = (t & 3) * 16;
  u16 buf[16];
  #pragma unroll
  for (int j = 0; j < 16; ++j) {
    int c = fc + j;
    int m = c & 31;
    int a = ((m & 4) << 2) | ((m & 16) >> 1) | ((m & 8) >> 1) | (m & 3);
    buf[j] = T[(c & 32) | a][dl];
  }
  u16* dst = Vt + (size_t)bh * 65536 + (size_t)dl * 1024 + f0 + fc;
  *(int4*)dst       = *(int4*)&buf[0];
  *(int4*)(dst + 8) = *(int4*)&buf[8];
}

// ---------------------------------------------------------------------------
// Kernel 4: flash attention v5 — LDS-staged dbuf K/V + lean softmax.
//  - QK accumulator seeded with -m: common path has NO subtracts.
//  - v_cvt_pk_bf16_f32 packing (1 op / 2 scores).
//  - max3-shaped reduction tree; defer-max rescale branch (rare, wave-uniform).
//  - setprio(1) around MFMA clusters.
// ---------------------------------------------------------------------------
__global__ __launch_bounds__(256) void attn_kernel(
    const u16* __restrict__ qkv, const u16* __restrict__ Vt,
    float* __restrict__ out) {
  const int F = 1024, NQ = 3072;
  int bid = blockIdx.x;           // 2048 blocks
  int xcd = bid & 7;
  int li  = bid >> 3;             // 0..255
  int bh  = ((li >> 4) << 3) | xcd;
  int ql  = li & 15;
  int w   = threadIdx.x >> 6;
  int lane = threadIdx.x & 63;
  int q = lane & 15, g = lane >> 4;
  int qs = q & 7;
  int q0 = ql * 64 + w * 16;
  int b = bh >> 4, h = bh & 15;

  const u16* base = qkv + (size_t)b * F * NQ + h * 192;
  const u16* VtBH = Vt + (size_t)bh * 65536;

  __shared__ u16 S[16384];

  int i8 = lane >> 3;     // staging row within wave's slice
  int ic = lane & 7;      // staging chunk (16B units)

  // Q fragment, pre-scaled by 1/8 * log2(e) -> softmax in exp2 domain
  const float qscale = 0.125f * 1.4426950408889634f;
  bf16x8 Qf0, Qf1;
  {
    const u16* qp = base + (size_t)(q0 + q) * NQ + g * 8;
    union { int4 v; u16 u[8]; } uu0, uu1;
    uu0.v = *(const int4*)(qp);
    uu1.v = *(const int4*)(qp + 32);
    union { u32 w4[4]; bf16x8 v; } p0, p1;
    #pragma unroll
    for (int j = 0; j < 4; ++j) {
      p0.w4[j] = cvtpk(bf2f(uu0.u[2 * j]) * qscale, bf2f(uu0.u[2 * j + 1]) * qscale);
      p1.w4[j] = cvtpk(bf2f(uu1.u[2 * j]) * qscale, bf2f(uu1.u[2 * j + 1]) * qscale);
    }
    Qf0 = p0.v; Qf1 = p1.v;
  }

  f32x4 acc[4] = {};
  float m = 0.0f, lsum = 0.f;   // m=0 init (C-seeding needs finite m; p<=2^8 bounded)

  #define STAGE(buf, kt)                                                       \
    do {                                                                       \
      int kb_ = (kt) * 64;                                                     \
      _Pragma("unroll")                                                        \
      for (int rr = 0; rr < 2; ++rr) {                                         \
        int r_ = rr * 32 + w * 8 + i8;                                         \
        int sc_ = (ic ^ (r_ & 7)) * 8;                                         \
        const u16* ks_ = base + (size_t)(kb_ + r_) * NQ + 64 + sc_;            \
        const u16* vs_ = VtBH + (size_t)r_ * 1024 + kb_ + sc_;                 \
        __builtin_amdgcn_global_load_lds((gas_ptr)ks_,                         \
            (las_ptr)&S[(buf) * 4096 + (rr * 32 + w * 8) * 64], 16, 0, 0);     \
        __builtin_amdgcn_global_load_lds((gas_ptr)vs_,                         \
            (las_ptr)&S[8192 + (buf) * 4096 + (rr * 32 + w * 8) * 64], 16, 0, 0);\
      }                                                                        \
    } while (0)

  STAGE(0, 0);
  __syncthreads();

  int cur = 0;
  for (int kt = 0; kt < 16; ++kt) {
    if (kt < 15) STAGE(cur ^ 1, kt + 1);

    const u16* Kb = &S[cur * 4096];
    const u16* Vb = &S[8192 + cur * 4096];

    // ---- QK^T with C seeded by -m (softmax shift folded into MFMA)
    f32x4 s[4];
    f32x4 seed = {-m, -m, -m, -m};
    __builtin_amdgcn_s_setprio(1);
    #pragma unroll
    for (int ks = 0; ks < 4; ++ks) {
      int row = ks * 16 + q;
      int4 k0 = *(const int4*)&Kb[row * 64 + ((g ^ qs) * 8)];
      int4 k1 = *(const int4*)&Kb[row * 64 + (((4 + g) ^ qs) * 8)];
      f32x4 sv = seed;
      sv = __builtin_amdgcn_mfma_f32_16x16x32_bf16(__builtin_bit_cast(bf16x8, k0), Qf0, sv, 0, 0, 0);
      sv = __builtin_amdgcn_mfma_f32_16x16x32_bf16(__builtin_bit_cast(bf16x8, k1), Qf1, sv, 0, 0, 0);
      s[ks] = sv;
    }
    __builtin_amdgcn_s_setprio(0);

    // ---- per-lane max, max3-shaped tree (s' = qk - m already)
    float a0 = fmaxf(fmaxf(s[0][0], s[0][1]), s[0][2]);
    float a1 = fmaxf(fmaxf(s[0][3], s[1][0]), s[1][1]);
    float a2 = fmaxf(fmaxf(s[1][2], s[1][3]), s[2][0]);
    float a3 = fmaxf(fmaxf(s[2][1], s[2][2]), s[2][3]);
    float a4 = fmaxf(fmaxf(s[3][0], s[3][1]), s[3][2]);
    float tmx = fmaxf(fmaxf(fmaxf(a0, a1), a2), fmaxf(fmaxf(a3, a4), s[3][3]));

    float p[16];
    if (__builtin_expect(__any(tmx > 8.0f), 0)) {
      // rare: rescale to new running max
      float tr = fmaxf(tmx, __shfl_xor(tmx, 16, 64));
      tr = fmaxf(tr, __shfl_xor(tr, 32, 64));
      float dm = fmaxf(tr, 0.f);
      float alpha = exp2f(-dm);
      lsum *= alpha;
      acc[0] *= alpha; acc[1] *= alpha; acc[2] *= alpha; acc[3] *= alpha;
      m += dm;
      #pragma unroll
      for (int ks = 0; ks < 4; ++ks) {
        p[ks * 4 + 0] = exp2f(s[ks][0] - dm);
        p[ks * 4 + 1] = exp2f(s[ks][1] - dm);
        p[ks * 4 + 2] = exp2f(s[ks][2] - dm);
        p[ks * 4 + 3] = exp2f(s[ks][3] - dm);
      }
    } else {
      #pragma unroll
      for (int ks = 0; ks < 4; ++ks) {
        p[ks * 4 + 0] = exp2f(s[ks][0]);
        p[ks * 4 + 1] = exp2f(s[ks][1]);
        p[ks * 4 + 2] = exp2f(s[ks][2]);
        p[ks * 4 + 3] = exp2f(s[ks][3]);
      }
    }
    // balanced psum tree
    float q01 = p[0] + p[1],   q23 = p[2] + p[3];
    float q45 = p[4] + p[5],   q67 = p[6] + p[7];
    float q89 = p[8] + p[9],   qab = p[10] + p[11];
    float qcd = p[12] + p[13], qef = p[14] + p[15];
    lsum += ((q01 + q23) + (q45 + q67)) + ((q89 + qab) + (qcd + qef));

    // ---- pack P via hw cvt_pk (keys pre-permuted in Vt)
    union { u32 w4[4]; bf16x8 v; } pb0, pb1;
    pb0.w4[0] = cvtpk(p[0], p[1]);   pb0.w4[1] = cvtpk(p[2], p[3]);
    pb0.w4[2] = cvtpk(p[4], p[5]);   pb0.w4[3] = cvtpk(p[6], p[7]);
    pb1.w4[0] = cvtpk(p[8], p[9]);   pb1.w4[1] = cvtpk(p[10], p[11]);
    pb1.w4[2] = cvtpk(p[12], p[13]); pb1.w4[3] = cvtpk(p[14], p[15]);

    // ---- PV
    __builtin_amdgcn_s_setprio(1);
    #pragma unroll
    for (int dt = 0; dt < 4; ++dt) {
      int row = dt * 16 + q;
      int4 v0 = *(const int4*)&Vb[row * 64 + ((g ^ qs) * 8)];
      int4 v1 = *(const int4*)&Vb[row * 64 + (((4 + g) ^ qs) * 8)];
      acc[dt] = __builtin_amdgcn_mfma_f32_16x16x32_bf16(__builtin_bit_cast(bf16x8, v0), pb0.v, acc[dt], 0, 0, 0);
      acc[dt] = __builtin_amdgcn_mfma_f32_16x16x32_bf16(__builtin_bit_cast(bf16x8, v1), pb1.v, acc[dt], 0, 0, 0);
    }
    __builtin_amdgcn_s_setprio(0);

    __syncthreads();
    cur ^= 1;
  }
  #undef STAGE

  // ---- epilogue: reduce lsum, normalize, transpose via LDS (aliased), store
  lsum += __shfl_xor(lsum, 16, 64);
  lsum += __shfl_xor(lsum, 32, 64);
  float inv = 1.0f / lsum;

  float* oT = (float*)S + (size_t)w * 1088;   // per-wave 64x17 region
  #pragma unroll
  for (int dt = 0; dt < 4; ++dt) {
    oT[(dt * 16 + g * 4 + 0) * 17 + q] = acc[dt][0] * inv;
    oT[(dt * 16 + g * 4 + 1) * 17 + q] = acc[dt][1] * inv;
    oT[(dt * 16 + g * 4 + 2) * 17 + q] = acc[dt][2] * inv;
    oT[(dt * 16 + g * 4 + 3) * 17 + q] = acc[dt][3] * inv;
  }
  asm volatile("s_waitcnt lgkmcnt(0)" ::: "memory");
  int oq = lane >> 2, dc = (lane & 3) * 16;
  float* orow = out + (size_t)(b * F + q0 + oq) * 1024 + h * 64 + dc;
  #pragma unroll
  for (int c4 = 0; c4 < 4; ++c4) {
    float4 v;
    v.x = oT[(dc + c4 * 4 + 0) * 17 + oq];
    v.y = oT[(dc + c4 * 4 + 1) * 17 + oq];
    v.z = oT[(dc + c4 * 4 + 2) * 17 + oq];
    v.w = oT[(dc + c4 * 4 + 3) * 17 + oq];
    *(float4*)(orow + c4 * 4) = v;
  }
}

// ---------------------------------------------------------------------------
extern "C" void kernel_launch(void* const* d_in, const int* in_sizes, int n_in,
                              void* d_out, int out_size, void* d_ws, size_t ws_size,
                              hipStream_t stream) {
  const float* x     = (const float*)d_in[0];
  const float* gamma = (const float*)d_in[1];
  const float* beta  = (const float*)d_in[2];
  const float* W     = (const float*)d_in[3];
  const float* bias  = (const float*)d_in[4];
  float* out = (float*)d_out;

  char* ws = (char*)d_ws;
  u16* xn  = (u16*)ws;                                   // 16 MB
  u16* Wb  = (u16*)(ws + (size_t)16 * 1024 * 1024);      //  6 MB
  u16* qkv = (u16*)(ws + (size_t)22 * 1024 * 1024);      // 48 MB
  u16* Vt  = (u16*)(ws + (size_t)70 * 1024 * 1024);      // 16 MB

  bn_norm_kernel<<<1024, 256, 0, stream>>>(x, gamma, beta, xn);
  wconv_kernel<<<768, 256, 0, stream>>>(W, Wb);
  gemm_qkv_kernel<<<dim3(64, 24), 256, 0, stream>>>(xn, Wb, bias, qkv);
  vt_kernel<<<dim3(16, 128), 256, 0, stream>>>(qkv, Vt);
  attn_kernel<<<2048, 256, 0, stream>>>(qkv, Vt, out);
}